// Round 7
// baseline (154.348 us; speedup 1.0000x reference)
//
#include <hip/hip_runtime.h>

#define N_NODES 50000
#define N_EDGES 800000
#define D_IN 96
#define HID 64
#define D_OUT 16

#define EPB 2048                                   // edges per block (passes A/C)
#define NBLK_E ((N_EDGES + EPB - 1) / EPB)         // 391
#define BSHIFT 7                                   // 128 nodes per bucket
#define NBKT ((N_NODES + 127) / 128)               // 391
#define DCAP 2560                                  // Ddst LDS edge staging cap

typedef unsigned short u16;
typedef unsigned int u32;
typedef __attribute__((ext_vector_type(4))) float f32x4;
typedef __attribute__((ext_vector_type(8))) short bf16x8;

__device__ inline float bflo(u32 v) { union { u32 i; float f; } u; u.i = v << 16; return u.f; }
__device__ inline float bfhi(u32 v) { union { u32 i; float f; } u; u.i = v & 0xffff0000u; return u.f; }
__device__ inline u16 f2bf(float f) {              // RTNE
    union { float f; u32 i; } u; u.f = f;
    return (u16)((u.i + 0x7fffu + ((u.i >> 16) & 1u)) >> 16);
}
__device__ inline u32 pack2(float lo, float hi) {
    return (u32)f2bf(lo) | ((u32)f2bf(hi) << 16);
}

// ============ CSR build: two-level counting sort, zero global atomics ============

__global__ __launch_bounds__(256)
void passA(const int* __restrict__ src, const int* __restrict__ dst,
           int* __restrict__ blk_cnt_src, int* __restrict__ blk_cnt_dst) {
    __shared__ int hs[NBKT], hd[NBKT];
    const int t = threadIdx.x, blk = blockIdx.x;
    for (int i = t; i < NBKT; i += 256) { hs[i] = 0; hd[i] = 0; }
    __syncthreads();
    const int e0 = blk * EPB;
    const int e1 = (e0 + EPB < N_EDGES) ? e0 + EPB : N_EDGES;
    for (int e = e0 + t; e < e1; e += 256) {
        atomicAdd(&hs[src[e] >> BSHIFT], 1);
        atomicAdd(&hd[dst[e] >> BSHIFT], 1);
    }
    __syncthreads();
    for (int b = t; b < NBKT; b += 256) {
        blk_cnt_src[b * NBLK_E + blk] = hs[b];
        blk_cnt_dst[b * NBLK_E + blk] = hd[b];
    }
}

__global__ __launch_bounds__(64)
void passB(int* __restrict__ blk_cnt_src, int* __restrict__ blk_cnt_dst,
           int* __restrict__ tot_src, int* __restrict__ tot_dst) {
    const int b = blockIdx.x;
    int* cnt; int* tot;
    if (b < NBKT) { cnt = blk_cnt_dst + b * NBLK_E;          tot = tot_dst + b; }
    else          { cnt = blk_cnt_src + (b - NBKT) * NBLK_E; tot = tot_src + (b - NBKT); }
    const int lane = threadIdx.x;
    int carry = 0;
    for (int base = 0; base < NBLK_E; base += 64) {
        int i = base + lane;
        int v = (i < NBLK_E) ? cnt[i] : 0;
        int incl = v;
        #pragma unroll
        for (int off = 1; off < 64; off <<= 1) {
            int x = __shfl_up(incl, off);
            if (lane >= off) incl += x;
        }
        if (i < NBLK_E) cnt[i] = carry + incl - v;
        carry += __shfl(incl, 63);
    }
    if (lane == 0) *tot = carry;
}

__global__ __launch_bounds__(256)
void passB2(const int* __restrict__ tot_src, const int* __restrict__ tot_dst,
            int* __restrict__ base_src, int* __restrict__ base_dst, int* __restrict__ row_ptr) {
    __shared__ int s[512];
    const int t = threadIdx.x;
    for (int pass = 0; pass < 2; ++pass) {
        const int* tot = pass ? tot_src : tot_dst;
        int* bas = pass ? base_src : base_dst;
        s[t]       = (t < NBKT) ? tot[t] : 0;
        s[t + 256] = (t + 256 < NBKT) ? tot[t + 256] : 0;
        __syncthreads();
        for (int off = 1; off < 512; off <<= 1) {
            int a1 = (t >= off) ? s[t - off] : 0;
            int a2 = (t + 256 >= off) ? s[t + 256 - off] : 0;
            __syncthreads();
            s[t] += a1; s[t + 256] += a2;
            __syncthreads();
        }
        if (t == 0) bas[0] = 0;
        if (t < NBKT) bas[t + 1] = s[t];
        if (t + 256 < NBKT) bas[t + 257] = s[t + 256];
        __syncthreads();
    }
    if (t == 0) row_ptr[N_NODES] = N_EDGES;
}

// Pass C: scatter edges into coarse-bucket-sorted arrays; dst side as int2 pairs.
__global__ __launch_bounds__(256)
void passC(const int* __restrict__ src, const int* __restrict__ dst,
           const int* __restrict__ blk_off_src, const int* __restrict__ blk_off_dst,
           const int* __restrict__ base_src, const int* __restrict__ base_dst,
           int* __restrict__ sorted_srconly, int2* __restrict__ sorted_pair) {
    __shared__ int cs[NBKT], cd[NBKT];
    const int t = threadIdx.x, blk = blockIdx.x;
    for (int b = t; b < NBKT; b += 256) {
        cs[b] = base_src[b] + blk_off_src[b * NBLK_E + blk];
        cd[b] = base_dst[b] + blk_off_dst[b * NBLK_E + blk];
    }
    __syncthreads();
    const int e0 = blk * EPB;
    const int e1 = (e0 + EPB < N_EDGES) ? e0 + EPB : N_EDGES;
    for (int e = e0 + t; e < e1; e += 256) {
        int sv = src[e], dv = dst[e];
        int ps = atomicAdd(&cs[sv >> BSHIFT], 1);
        sorted_srconly[ps] = sv;
        int pd = atomicAdd(&cd[dv >> BSHIFT], 1);
        sorted_pair[pd] = make_int2(dv, sv);
    }
}

__global__ __launch_bounds__(256)
void passDsrc(const int* __restrict__ base_src, const int* __restrict__ sorted_srconly,
              float* __restrict__ dis) {
    __shared__ int hist[128];
    const int b = blockIdx.x, t = threadIdx.x;
    if (t < 128) hist[t] = 0;
    __syncthreads();
    const int eb = base_src[b], ee = base_src[b + 1];
    for (int i = eb + t; i < ee; i += 256)
        atomicAdd(&hist[sorted_srconly[i] & 127], 1);
    __syncthreads();
    const int node = (b << BSHIFT) + t;
    if (t < 128 && node < N_NODES) {
        int c = hist[t];
        dis[node] = c > 0 ? rsqrtf((float)c) : 0.0f;
    }
}

// Pass Ddst: per-bucket fine CSR: row_ptr, node-grouped wpair = {src, -dis[s]*dis[d]}.
__global__ __launch_bounds__(256)
void passDdst(const int* __restrict__ base_dst, const int2* __restrict__ sorted_pair,
              const float* __restrict__ dis,
              int* __restrict__ row_ptr, int2* __restrict__ wpair) {
    __shared__ int s_d[DCAP];
    __shared__ int s_s[DCAP];
    __shared__ int hist[128];
    __shared__ int cur[128];
    __shared__ float s_dis[128];
    const int b = blockIdx.x, t = threadIdx.x;
    if (t < 128) {
        hist[t] = 0;
        int node = (b << BSHIFT) + t;
        s_dis[t] = (node < N_NODES) ? dis[node] : 0.0f;
    }
    __syncthreads();
    const int eb = base_dst[b], ee = base_dst[b + 1];
    const int cnt = ee - eb;
    const int stage = cnt < DCAP ? cnt : DCAP;
    for (int i = t; i < stage; i += 256) {
        int2 p = sorted_pair[eb + i];
        int d = p.x & 127;
        s_d[i] = d;
        s_s[i] = p.y;
        atomicAdd(&hist[d], 1);
    }
    for (int i = stage + t; i < cnt; i += 256)
        atomicAdd(&hist[sorted_pair[eb + i].x & 127], 1);
    __syncthreads();
    if (t < 64) {
        int v0 = hist[2 * t], v1 = hist[2 * t + 1];
        int p = v0 + v1;
        int incl = p;
        #pragma unroll
        for (int off = 1; off < 64; off <<= 1) {
            int x = __shfl_up(incl, off);
            if (t >= off) incl += x;
        }
        int excl = incl - p;
        cur[2 * t] = excl;
        cur[2 * t + 1] = excl + v0;
        int node = (b << BSHIFT) + 2 * t;
        if (node < N_NODES) row_ptr[node] = eb + excl;
        if (node + 1 < N_NODES) row_ptr[node + 1] = eb + excl + v0;
    }
    __syncthreads();
    for (int i = t; i < stage; i += 256) {
        int ln = s_d[i], sv = s_s[i];
        int slot = atomicAdd(&cur[ln], 1);
        wpair[eb + slot] = make_int2(sv, __float_as_int(-dis[sv] * s_dis[ln]));
    }
    for (int i = stage + t; i < cnt; i += 256) {
        int2 p = sorted_pair[eb + i];
        int ln = p.x & 127, sv = p.y;
        int slot = atomicAdd(&cur[ln], 1);
        wpair[eb + slot] = make_int2(sv, __float_as_int(-dis[sv] * s_dis[ln]));
    }
}

// ============ MFMA GEMM with in-kernel weight pack, plane-split output ============
// col c = ct*16+r16 stored at Z + (ct/CPK)*CBS + node*LDZ + (ct%CPK)*16 + r16

template<int K, int NC, int OUTW, int LDZ, int CPK, long CBS, bool AF32>
__global__ __launch_bounds__(256)
void gemm_mfma(const void* __restrict__ Av, const float* __restrict__ W, u16* __restrict__ Z) {
    constexpr int KT = K / 32;
    constexpr int TOT = K * NC;
    __shared__ u16 sP[TOT];
    // pack W[kc][i][o] (f32) -> MFMA B-fragment order (bf16)
    for (int t = threadIdx.x; t < TOT; t += 256) {
        int j = t & 7, rest = t >> 3;
        int c = rest % NC, i = (rest / NC) * 8 + j;
        int kc = c / OUTW, o = c % OUTW;
        sP[t] = f2bf(W[((long)kc * K + i) * OUTW + o]);
    }
    __syncthreads();
    const int lane = threadIdx.x & 63;
    const int tile = blockIdx.x * 4 + (threadIdx.x >> 6);
    if (tile * 16 >= N_NODES) return;
    const int node0 = tile * 16;
    const int sub = lane >> 4, r16 = lane & 15;
    bf16x8 a[KT];
    if (AF32) {
        const float* ar = (const float*)Av + (long)(node0 + r16) * K + sub * 8;
        #pragma unroll
        for (int kt = 0; kt < KT; ++kt) {
            float4 a0 = *(const float4*)(ar + kt * 32);
            float4 a1 = *(const float4*)(ar + kt * 32 + 4);
            union { bf16x8 v; uint4 q; } u;
            u.q.x = pack2(a0.x, a0.y); u.q.y = pack2(a0.z, a0.w);
            u.q.z = pack2(a1.x, a1.y); u.q.w = pack2(a1.z, a1.w);
            a[kt] = u.v;
        }
    } else {
        const u16* ar = (const u16*)Av + (long)(node0 + r16) * K + sub * 8;
        #pragma unroll
        for (int kt = 0; kt < KT; ++kt)
            a[kt] = *(const bf16x8*)(ar + kt * 32);
    }
    #pragma unroll
    for (int ct = 0; ct < NC / 16; ++ct) {
        f32x4 acc = {0.f, 0.f, 0.f, 0.f};
        #pragma unroll
        for (int kt = 0; kt < KT; ++kt) {
            bf16x8 bfr = *(const bf16x8*)&sP[((kt * 4 + sub) * NC + ct * 16 + r16) * 8];
            acc = __builtin_amdgcn_mfma_f32_16x16x32_bf16(a[kt], bfr, acc, 0, 0, 0);
        }
        u16* zp = Z + (long)(ct / CPK) * CBS + (long)(node0 + sub * 4) * LDZ + (ct % CPK) * 16 + r16;
        #pragma unroll
        for (int r = 0; r < 4; ++r)
            zp[(long)r * LDZ] = f2bf(acc[r]);
    }
}

// ============ gather propagate: LDS-free, 8-way MLP, fused Cheb epilogues ============
// EPI_S  : S   = aux1 + 2*acc                      (bf16 out)
// EPI_H  : h   = relu(aux1 - aux2 + acc + bias)    (bf16 out)
// EPI_OUT: out = aux1 - aux2 + acc + bias          (f32 out)

#define EPI_S 0
#define EPI_H 1
#define EPI_OUT 2

__device__ inline void accum8(float (&acc)[8], float we, uint4 q) {
    acc[0] = fmaf(we, bflo(q.x), acc[0]);
    acc[1] = fmaf(we, bfhi(q.x), acc[1]);
    acc[2] = fmaf(we, bflo(q.y), acc[2]);
    acc[3] = fmaf(we, bfhi(q.y), acc[3]);
    acc[4] = fmaf(we, bflo(q.z), acc[4]);
    acc[5] = fmaf(we, bfhi(q.z), acc[5]);
    acc[6] = fmaf(we, bflo(q.w), acc[6]);
    acc[7] = fmaf(we, bfhi(q.w), acc[7]);
}

template<int F, int EPI>
__global__ __launch_bounds__(256)
void gather_prop(const int* __restrict__ row_ptr, const int2* __restrict__ wp,
                 const u16* __restrict__ g,       // gather source plane [N,F]
                 const u16* __restrict__ aux1,
                 const u16* __restrict__ aux2,
                 const float* __restrict__ bias,
                 void* __restrict__ outp) {
    constexpr int CPN = F / 8;
    const int t = blockIdx.x * blockDim.x + threadIdx.x;
    const int node = t / CPN;
    if (node >= N_NODES) return;
    const int c8 = (t % CPN) * 8;
    const int beg = row_ptr[node], end = row_ptr[node + 1];
    float acc[8];
    #pragma unroll
    for (int j = 0; j < 8; ++j) acc[j] = 0.0f;
    int e = beg;
    for (; e + 8 <= end; e += 8) {                 // 8-way MLP
        int2 p0 = wp[e],     p1 = wp[e + 1], p2 = wp[e + 2], p3 = wp[e + 3];
        int2 p4 = wp[e + 4], p5 = wp[e + 5], p6 = wp[e + 6], p7 = wp[e + 7];
        uint4 q0 = *(const uint4*)(g + (long)p0.x * F + c8);
        uint4 q1 = *(const uint4*)(g + (long)p1.x * F + c8);
        uint4 q2 = *(const uint4*)(g + (long)p2.x * F + c8);
        uint4 q3 = *(const uint4*)(g + (long)p3.x * F + c8);
        uint4 q4 = *(const uint4*)(g + (long)p4.x * F + c8);
        uint4 q5 = *(const uint4*)(g + (long)p5.x * F + c8);
        uint4 q6 = *(const uint4*)(g + (long)p6.x * F + c8);
        uint4 q7 = *(const uint4*)(g + (long)p7.x * F + c8);
        accum8(acc, __int_as_float(p0.y), q0); accum8(acc, __int_as_float(p1.y), q1);
        accum8(acc, __int_as_float(p2.y), q2); accum8(acc, __int_as_float(p3.y), q3);
        accum8(acc, __int_as_float(p4.y), q4); accum8(acc, __int_as_float(p5.y), q5);
        accum8(acc, __int_as_float(p6.y), q6); accum8(acc, __int_as_float(p7.y), q7);
    }
    for (; e + 4 <= end; e += 4) {                 // 4-way middle
        int2 p0 = wp[e], p1 = wp[e + 1], p2 = wp[e + 2], p3 = wp[e + 3];
        uint4 q0 = *(const uint4*)(g + (long)p0.x * F + c8);
        uint4 q1 = *(const uint4*)(g + (long)p1.x * F + c8);
        uint4 q2 = *(const uint4*)(g + (long)p2.x * F + c8);
        uint4 q3 = *(const uint4*)(g + (long)p3.x * F + c8);
        accum8(acc, __int_as_float(p0.y), q0); accum8(acc, __int_as_float(p1.y), q1);
        accum8(acc, __int_as_float(p2.y), q2); accum8(acc, __int_as_float(p3.y), q3);
    }
    for (; e < end; ++e) {
        int2 p = wp[e];
        uint4 q = *(const uint4*)(g + (long)p.x * F + c8);
        accum8(acc, __int_as_float(p.y), q);
    }
    if (EPI == EPI_S) {
        const uint4 z1 = *(const uint4*)(aux1 + (long)node * F + c8);
        uint4 r;
        r.x = pack2(bflo(z1.x) + 2.f * acc[0], bfhi(z1.x) + 2.f * acc[1]);
        r.y = pack2(bflo(z1.y) + 2.f * acc[2], bfhi(z1.y) + 2.f * acc[3]);
        r.z = pack2(bflo(z1.z) + 2.f * acc[4], bfhi(z1.z) + 2.f * acc[5]);
        r.w = pack2(bflo(z1.w) + 2.f * acc[6], bfhi(z1.w) + 2.f * acc[7]);
        *(uint4*)((u16*)outp + (long)node * F + c8) = r;
    } else {
        const uint4 z0 = *(const uint4*)(aux1 + (long)node * F + c8);
        const uint4 z2 = *(const uint4*)(aux2 + (long)node * F + c8);
        const float* bb = bias + c8;
        float v0 = bflo(z0.x) - bflo(z2.x) + acc[0] + bb[0];
        float v1 = bfhi(z0.x) - bfhi(z2.x) + acc[1] + bb[1];
        float v2 = bflo(z0.y) - bflo(z2.y) + acc[2] + bb[2];
        float v3 = bfhi(z0.y) - bfhi(z2.y) + acc[3] + bb[3];
        float v4 = bflo(z0.z) - bflo(z2.z) + acc[4] + bb[4];
        float v5 = bfhi(z0.z) - bfhi(z2.z) + acc[5] + bb[5];
        float v6 = bflo(z0.w) - bflo(z2.w) + acc[6] + bb[6];
        float v7 = bfhi(z0.w) - bfhi(z2.w) + acc[7] + bb[7];
        if (EPI == EPI_H) {
            uint4 r;
            r.x = pack2(fmaxf(v0, 0.f), fmaxf(v1, 0.f));
            r.y = pack2(fmaxf(v2, 0.f), fmaxf(v3, 0.f));
            r.z = pack2(fmaxf(v4, 0.f), fmaxf(v5, 0.f));
            r.w = pack2(fmaxf(v6, 0.f), fmaxf(v7, 0.f));
            *(uint4*)((u16*)outp + (long)node * F + c8) = r;
        } else {
            float* op = (float*)outp + (long)node * F + c8;
            *(float4*)op = make_float4(v0, v1, v2, v3);
            *(float4*)(op + 4) = make_float4(v4, v5, v6, v7);
        }
    }
}

// ============ launch ============

extern "C" void kernel_launch(void* const* d_in, const int* in_sizes, int n_in,
                              void* d_out, int out_size, void* d_ws, size_t ws_size,
                              hipStream_t stream) {
    const float* x  = (const float*)d_in[0];
    const int*   ei = (const int*)d_in[1];
    const float* W1 = (const float*)d_in[2];
    const float* b1 = (const float*)d_in[3];
    const float* W2 = (const float*)d_in[4];
    const float* b2 = (const float*)d_in[5];
    const int* src = ei;
    const int* dst = ei + N_EDGES;

    // ---- workspace (sections aligned; u16 region starts 16B-aligned) ----
    float* dis          = (float*)d_ws;                      // 50000
    int*   row_ptr      = (int*)(dis + N_NODES);             // 50016
    int*   blk_cnt_src  = row_ptr + 50016;                   // 152896
    int*   blk_cnt_dst  = blk_cnt_src + 152896;              // 152896
    int*   tot_src      = blk_cnt_dst + 152896;              // 512
    int*   tot_dst      = tot_src + 512;                     // 512
    int*   base_src     = tot_dst + 512;                     // 512
    int*   base_dst     = base_src + 512;                    // 512
    int*   srconly      = base_dst + 512;                    // E
    int2*  sorted_pair  = (int2*)(srconly + N_EDGES);        // E int2
    int2*  wpair        = sorted_pair + N_EDGES;             // E int2
    u16*   Z            = (u16*)(wpair + N_EDGES);           // [3 planes][N][64]
    u16*   S            = Z + (long)3 * N_NODES * HID;       // N*64
    u16*   hb           = S + (long)N_NODES * HID;           // N*64
    u16*   Zp           = hb + (long)N_NODES * HID;          // [3 planes][N][16]
    u16*   Sp           = Zp + (long)3 * N_NODES * D_OUT;    // N*16

    const long PZ  = (long)N_NODES * HID;    // layer-1 plane stride
    const long PZp = (long)N_NODES * D_OUT;  // layer-2 plane stride

    // ---- CSR build (no global atomics) ----
    passA<<<NBLK_E, 256, 0, stream>>>(src, dst, blk_cnt_src, blk_cnt_dst);
    passB<<<2 * NBKT, 64, 0, stream>>>(blk_cnt_src, blk_cnt_dst, tot_src, tot_dst);
    passB2<<<1, 256, 0, stream>>>(tot_src, tot_dst, base_src, base_dst, row_ptr);
    passC<<<NBLK_E, 256, 0, stream>>>(src, dst, blk_cnt_src, blk_cnt_dst, base_src, base_dst,
                                      srconly, sorted_pair);
    passDsrc<<<NBKT, 256, 0, stream>>>(base_src, srconly, dis);
    passDdst<<<NBKT, 256, 0, stream>>>(base_dst, sorted_pair, dis, row_ptr, wpair);

    // ---- layer 1: Z = x @ W1 (planes Z0|Z1|Z2), S = Z1 + 2 L Z2, h = relu(Z0 - Z2 + L S + b1) ----
    const int GB = (N_NODES / 16 + 3) / 4;   // 782
    gemm_mfma<D_IN, 192, HID, HID, 4, (long)N_NODES * HID, true><<<GB, 256, 0, stream>>>(x, W1, Z);
    gather_prop<HID, EPI_S><<<(N_NODES * (HID / 8) + 255) / 256, 256, 0, stream>>>(
        row_ptr, wpair, Z + 2 * PZ, Z + PZ, nullptr, nullptr, S);
    gather_prop<HID, EPI_H><<<(N_NODES * (HID / 8) + 255) / 256, 256, 0, stream>>>(
        row_ptr, wpair, S, Z, Z + 2 * PZ, b1, hb);

    // ---- layer 2: Zp = h @ W2 (planes), Sp = Z'1 + 2 L Z'2, out = Z'0 - Z'2 + L Sp + b2 ----
    gemm_mfma<HID, 48, D_OUT, D_OUT, 1, (long)N_NODES * D_OUT, false><<<GB, 256, 0, stream>>>(hb, W2, Zp);
    gather_prop<D_OUT, EPI_S><<<(N_NODES * (D_OUT / 8) + 255) / 256, 256, 0, stream>>>(
        row_ptr, wpair, Zp + 2 * PZp, Zp + PZp, nullptr, nullptr, Sp);
    gather_prop<D_OUT, EPI_OUT><<<(N_NODES * (D_OUT / 8) + 255) / 256, 256, 0, stream>>>(
        row_ptr, wpair, Sp, Zp, Zp + 2 * PZp, b2, (float*)d_out);
}